// Round 8
// baseline (362.031 us; speedup 1.0000x reference)
//
#include <hip/hip_runtime.h>
#include <hip/hip_bf16.h>

#define OUT1 16777216    // 4*64*256*256
#define BIG  33554432    // 4*128*256*256

typedef _Float16 half8 __attribute__((ext_vector_type(8)));
typedef float    floatx4 __attribute__((ext_vector_type(4)));

struct __align__(8) h4s { _Float16 x, y, z, w; };
__device__ inline void store4h(_Float16* p, float4 v){
    h4s t; t.x = (_Float16)v.x; t.y = (_Float16)v.y; t.z = (_Float16)v.z; t.w = (_Float16)v.w;
    *(h4s*)p = t;
}

// ---------------- K1: bilinear upsample 64x64 -> 256x256 (align_corners) + clip ----------------
__global__ __launch_bounds__(256) void k_prior(const float* __restrict__ prior, float* __restrict__ pu){
    int i = blockIdx.x*256 + threadIdx.x;       // 0..262143
    int b = i >> 16;
    int rem = i & 65535;
    int yy = rem >> 8, xx = rem & 255;
    const float scale = 63.0f/255.0f;
    float sy = yy*scale, sx = xx*scale;
    int y0 = min((int)floorf(sy), 63), x0 = min((int)floorf(sx), 63);
    int y1 = min(y0+1, 63), x1 = min(x0+1, 63);
    float wy = sy - (float)y0, wx = sx - (float)x0;
    const float* pb = prior + (b<<12);
    float v00 = pb[(y0<<6)+x0], v01 = pb[(y0<<6)+x1];
    float v10 = pb[(y1<<6)+x0], v11 = pb[(y1<<6)+x1];
    float r0 = v00*(1.f-wy) + v10*wy;
    float r1 = v01*(1.f-wy) + v11*wy;
    float v  = r0*(1.f-wx) + r1*wx;
    pu[i] = fminf(fmaxf(v, -1.f), 1.f);
}

// ---------------- K0: fold weights (f16): Wch(384x64), biases, -exp(A), Wof(64x128) ----------
__global__ __launch_bounds__(256) void k_comb(const float* __restrict__ W_in, const float* __restrict__ b_in,
        const float* __restrict__ W_delta, const float* __restrict__ b_delta,
        const float* __restrict__ W_B, const float* __restrict__ b_B,
        const float* __restrict__ A_param, const float* __restrict__ W_out,
        _Float16* __restrict__ Wch, float* __restrict__ bcv, float* __restrict__ negA,
        _Float16* __restrict__ Wof){
    int i = blockIdx.x*256 + threadIdx.x;
    if (i < 24576){
        int r = i >> 6, c = i & 63;
        float v;
        if (r < 128) v = W_in[i];
        else if (r < 256){
            int rr = r-128; float s = 0.f;
            for (int k=0;k<128;k++) s = fmaf(W_delta[(rr<<7)+k], W_in[(k<<6)+c], s);
            v = s;
        } else {
            int rr = r-256; float s = 0.f;
            for (int k=0;k<128;k++) s = fmaf(W_B[(rr<<7)+k], W_in[(k<<6)+c], s);
            v = s;
        }
        Wch[i] = (_Float16)v;
    } else if (i < 24960){
        int r = i - 24576; float v;
        if (r < 128) v = b_in[r];
        else if (r < 256){
            int rr=r-128; float s = b_delta[rr];
            for (int k=0;k<128;k++) s = fmaf(W_delta[(rr<<7)+k], b_in[k], s);
            v = s;
        } else {
            int rr=r-256; float s = b_B[rr];
            for (int k=0;k<128;k++) s = fmaf(W_B[(rr<<7)+k], b_in[k], s);
            v = s;
        }
        bcv[r] = v;
    } else if (i < 25088){
        negA[i-24960] = -expf(A_param[i-24960]);
    } else if (i < 33280){
        Wof[i-25088] = (_Float16)W_out[i-25088];   // [o][k] row-major, 64x128
    }
}

// ---------------- K2: MFMA projection v3 — no LDS, B(W)-fragments from global (L1-hot) --------
// A = X (m=pixel), B = W (n=row); D: col=channel-in-tile, quad*4+r = pixel -> 8B stores.
// 8 independent ct-groups: 3 acc tiles live at a time -> low VGPR, high occupancy, no barrier.
__global__ __launch_bounds__(256, 4) void k_proj_mfma(const float* __restrict__ x, const float* __restrict__ pu,
        const _Float16* __restrict__ Wch, const float* __restrict__ bcv, const float* __restrict__ negA,
        const float* __restrict__ lam_p, const float* __restrict__ alp_p,
        _Float16* __restrict__ Ab, _Float16* __restrict__ Uu){
    const int t    = threadIdx.x;
    const int lane = t & 63;
    const int wave = t >> 6;
    const int col  = lane & 15;
    const int quad = lane >> 4;

    const int blk = blockIdx.x;                    // 0..4095
    const int b   = blk >> 10;
    const int p0  = (blk & 1023) << 6;             // 64-px chunk
    const int pxw = p0 + (wave << 4);              // this wave's 16-px tile

    // ---- A fragments: X[m=pxw+col][k=quad*8+j], f32 global -> f16, each x element read once ----
    const float* xb = x + ((size_t)b<<22) + pxw + col;
    half8 aX[2];
    #pragma unroll
    for (int kh = 0; kh < 2; kh++){
        half8 h;
        #pragma unroll
        for (int j = 0; j < 8; j++){
            int k = kh*32 + quad*8 + j;
            h[j] = (_Float16)xb[(size_t)k<<16];
        }
        aX[kh] = h;
    }

    // ---- prior factors for this lane's 4 consecutive px ----
    const float lamv = lam_p[0], alpv = alp_p[0];
    float4 puv4 = *(const float4*)(pu + (b<<16) + pxw + (quad<<2));
    float lpu[4], apu[4];
    #pragma unroll
    for (int r = 0; r < 4; r++){
        float pv = ((const float*)&puv4)[r];
        lpu[r] = lamv * pv;
        apu[r] = fmaf(alpv, pv, 1.f);
    }

    // ---- 8 ct-groups: rows {c, 128+c, 256+c}, c = ct*16+col ----
    #pragma unroll
    for (int ct = 0; ct < 8; ct++){
        int c = (ct<<4) + col;
        const _Float16* wI = Wch + ((size_t)c<<6)        + quad*8;
        const _Float16* wD = Wch + ((size_t)(128+c)<<6)  + quad*8;
        const _Float16* wB = Wch + ((size_t)(256+c)<<6)  + quad*8;
        half8 bI0 = *(const half8*)wI,        bI1 = *(const half8*)(wI+32);
        half8 bD0 = *(const half8*)wD,        bD1 = *(const half8*)(wD+32);
        half8 bB0 = *(const half8*)wB,        bB1 = *(const half8*)(wB+32);
        floatx4 aI = (floatx4){0.f,0.f,0.f,0.f};
        floatx4 aD = (floatx4){0.f,0.f,0.f,0.f};
        floatx4 aB = (floatx4){0.f,0.f,0.f,0.f};
        aI = __builtin_amdgcn_mfma_f32_16x16x32_f16(aX[0], bI0, aI, 0, 0, 0);
        aD = __builtin_amdgcn_mfma_f32_16x16x32_f16(aX[0], bD0, aD, 0, 0, 0);
        aB = __builtin_amdgcn_mfma_f32_16x16x32_f16(aX[0], bB0, aB, 0, 0, 0);
        aI = __builtin_amdgcn_mfma_f32_16x16x32_f16(aX[1], bI1, aI, 0, 0, 0);
        aD = __builtin_amdgcn_mfma_f32_16x16x32_f16(aX[1], bD1, aD, 0, 0, 0);
        aB = __builtin_amdgcn_mfma_f32_16x16x32_f16(aX[1], bB1, aB, 0, 0, 0);

        float bIc = bcv[c], bDc = bcv[128+c], bBc = bcv[256+c], nA = negA[c];
        h4s oa, ou;
        #pragma unroll
        for (int r = 0; r < 4; r++){
            float sI = aI[r] + bIc;
            float sD = aD[r] + bDc;
            float sB = aB[r] + bBc;
            float dpre  = sD + lpu[r];
            float delta = fmaxf(dpre, 0.f) + __logf(1.f + __expf(-fabsf(dpre)));
            float ab    = __expf(nA * delta);
            float uu    = delta * sB * apu[r] * sI;
            (&oa.x)[r] = (_Float16)ab;
            (&ou.x)[r] = (_Float16)uu;
        }
        size_t o = ((size_t)((b<<7) + c)<<16) + pxw + (quad<<2);
        *(h4s*)(Ab+o) = oa;
        *(h4s*)(Uu+o) = ou;
    }
}

// ---------------- K3: fused W-scan + H-scan, one wave per (b,c) plane -> Sh directly ----------
// Per h-row: wave-shuffle W-scan (4 px/lane) + register H-state update (4 cols/lane).
// Sh[h][w] = scanH[h][w] + scanW[h][w]. No Sw buffer, no second pass.
__global__ __launch_bounds__(64) void k_scan2(const _Float16* __restrict__ Ab, const _Float16* __restrict__ Uu,
                                              _Float16* __restrict__ Sh){
    const int plane = blockIdx.x;              // 0..511 = b*128+c
    const int lane  = threadIdx.x;             // 0..63
    size_t pbase = ((size_t)plane<<16) + (lane<<2);
    float h0=0.f, h1=0.f, h2=0.f, h3=0.f;      // H-state for this lane's 4 columns
    #pragma unroll 4
    for (int hh = 0; hh < 256; hh++){
        size_t base = pbase + ((size_t)hh<<8);
        h4s a4 = *(const h4s*)(Ab+base);
        h4s u4 = *(const h4s*)(Uu+base);
        float ax=(float)a4.x, ay=(float)a4.y, az=(float)a4.z, aw=(float)a4.w;
        float ux=(float)u4.x, uy=(float)u4.y, uz=(float)u4.z, uw=(float)u4.w;
        // W-scan: lane-local segment transform
        float A = ax, U = ux;
        U = fmaf(ay, U, uy); A *= ay;
        U = fmaf(az, U, uz); A *= az;
        U = fmaf(aw, U, uw); A *= aw;
        #pragma unroll
        for (int off=1; off<64; off<<=1){
            float Apv = __shfl_up(A, off, 64);
            float Upv = __shfl_up(U, off, 64);
            if (lane >= off){ U = fmaf(A, Upv, U); A *= Apv; }
        }
        float hw = __shfl_up(U, 1, 64);        // exclusive prefix entering this lane
        if (lane == 0) hw = 0.f;
        // H-state update (raw a,u per column)
        h0 = fmaf(ax, h0, ux);
        h1 = fmaf(ay, h1, uy);
        h2 = fmaf(az, h2, uz);
        h3 = fmaf(aw, h3, uw);
        // scanW inclusive values + scanH
        float4 o;
        hw = fmaf(ax, hw, ux); o.x = hw + h0;
        hw = fmaf(ay, hw, uy); o.y = hw + h1;
        hw = fmaf(az, hw, uz); o.z = hw + h2;
        hw = fmaf(aw, hw, uw); o.w = hw + h3;
        store4h(Sh+base, o);
    }
}

// ---------------- K5: MFMA output conv (128->64) + residual ----------------
// A = Wof[64][128] f16; B = Sh[k=128][n=px] f16; D: col=pixel, quad*4+r = out-ch within tile.
__global__ __launch_bounds__(256, 2) void k_out_mfma(const float* __restrict__ x, const _Float16* __restrict__ Sh,
        const _Float16* __restrict__ Wof, const float* __restrict__ bout, const float* __restrict__ gam_p,
        float* __restrict__ out){
    const int t    = threadIdx.x;
    const int lane = t & 63;
    const int wave = t >> 6;
    const int col  = lane & 15;
    const int quad = lane >> 4;
    const int b    = blockIdx.x >> 8;
    const int p0   = (blockIdx.x & 255) << 8;
    const int wn0  = wave << 6;

    const _Float16* shb = Sh + ((size_t)b<<23) + p0;

    floatx4 acc[4][4];
    #pragma unroll
    for (int mt = 0; mt < 4; mt++)
        #pragma unroll
        for (int nt = 0; nt < 4; nt++)
            acc[mt][nt] = (floatx4){0.f,0.f,0.f,0.f};

    #pragma unroll
    for (int kc = 0; kc < 4; kc++){
        half8 bf[4];
        #pragma unroll
        for (int nt = 0; nt < 4; nt++){
            int px = wn0 + nt*16 + col;
            #pragma unroll
            for (int j = 0; j < 8; j++)
                bf[nt][j] = shb[((size_t)(kc*32 + quad*8 + j)<<16) + px];
        }
        half8 af[4];
        #pragma unroll
        for (int mt = 0; mt < 4; mt++)
            af[mt] = *(const half8*)(Wof + (mt*16 + col)*128 + kc*32 + quad*8);
        #pragma unroll
        for (int mt = 0; mt < 4; mt++)
            #pragma unroll
            for (int nt = 0; nt < 4; nt++)
                acc[mt][nt] = __builtin_amdgcn_mfma_f32_16x16x32_f16(af[mt], bf[nt], acc[mt][nt], 0, 0, 0);
    }

    const float gv = gam_p[0];
    #pragma unroll
    for (int mt = 0; mt < 4; mt++){
        #pragma unroll
        for (int nt = 0; nt < 4; nt++){
            int px = wn0 + nt*16 + col;
            #pragma unroll
            for (int r = 0; r < 4; r++){
                int o = mt*16 + quad*4 + r;
                size_t idx = (((size_t)(b*64 + o))<<16) + p0 + px;
                out[idx] = fmaf(gv, acc[mt][nt][r] + bout[o], x[idx]);
            }
        }
    }
}

extern "C" void kernel_launch(void* const* d_in, const int* in_sizes, int n_in,
                              void* d_out, int out_size, void* d_ws, size_t ws_size,
                              hipStream_t stream){
    const float* x       = (const float*)d_in[0];
    const float* prior   = (const float*)d_in[1];
    const float* W_in    = (const float*)d_in[2];
    const float* b_in    = (const float*)d_in[3];
    const float* W_out   = (const float*)d_in[4];
    const float* b_out   = (const float*)d_in[5];
    const float* W_delta = (const float*)d_in[6];
    const float* b_delta = (const float*)d_in[7];
    const float* W_B     = (const float*)d_in[8];
    const float* b_B     = (const float*)d_in[9];
    const float* A_param = (const float*)d_in[10];
    const float* lam     = (const float*)d_in[11];
    const float* alp     = (const float*)d_in[12];
    const float* gam     = (const float*)d_in[13];

    float* out = (float*)d_out;
    float* pu  = out + OUT1;                   // prior_up = output 1

    float* ws        = (float*)d_ws;
    _Float16* Wch    = (_Float16*)ws;          // 24576 f16 -> float-offset [0,12288)
    float* bcv       = ws + 12288;             // 384
    float* negA      = ws + 12672;             // 128
    _Float16* Wof    = (_Float16*)(ws + 12800);// 8192 f16 -> [12800,16896)
    _Float16* AbH    = (_Float16*)(ws + 32768);// BIG f16
    _Float16* UuH    = AbH + BIG;              // BIG f16
    _Float16* Sh     = UuH + BIG;              // BIG f16   (total 201.5 MB)

    hipLaunchKernelGGL(k_prior,  dim3(1024),  dim3(256), 0, stream, prior, pu);
    hipLaunchKernelGGL(k_comb,   dim3(130),   dim3(256), 0, stream, W_in, b_in, W_delta, b_delta,
                       W_B, b_B, A_param, W_out, Wch, bcv, negA, Wof);
    hipLaunchKernelGGL(k_proj_mfma, dim3(4096), dim3(256), 0, stream,
                       x, pu, Wch, bcv, negA, lam, alp, AbH, UuH);
    hipLaunchKernelGGL(k_scan2, dim3(512), dim3(64), 0, stream, AbH, UuH, Sh);
    hipLaunchKernelGGL(k_out_mfma, dim3(1024), dim3(256), 0, stream, x, Sh, Wof, b_out, gam, out);
}